// Round 9
// baseline (4227.237 us; speedup 1.0000x reference)
//
#include <hip/hip_runtime.h>

#define H_ 128
#define T_ 1024
#define B_ 512
#define I_ 13
#define LOG2E 1.4426950408889634f

typedef _Float16 half8 __attribute__((ext_vector_type(8)));
typedef _Float16 half4 __attribute__((ext_vector_type(4)));
typedef float float4_ __attribute__((ext_vector_type(4)));

static __device__ __forceinline__ float fast_rcp(float v) {
  return __builtin_amdgcn_rcpf(v);
}
static __device__ __forceinline__ float fast_exp2(float v) {
  return __builtin_amdgcn_exp2f(v);
}
static __device__ __forceinline__ float sigmoid_f(float v) {
  return fast_rcp(1.0f + fast_exp2(-LOG2E * v));
}
static __device__ __forceinline__ float tanh_f(float v) {
  return 2.0f * fast_rcp(1.0f + fast_exp2(-2.0f * LOG2E * v)) - 1.0f;
}

// One WG per CU (256 WGs), 2 batch rows each, weights VGPR-resident.
// R9 = R5 skeleton (941 us verified; NO lambda, NO unroll -- R8 spilled) with:
//  - x*Wih on the VALU: thread tid owns gate col tid (13 Wih f32 weights in
//    regs, bias folded); computes xpart(t+1) for both rows during step t into
//    a padded LDS ring (stride 36 halfs -> conflict-free b64 reads).
//    K-loop 5->4 chunks: 164 -> 132 MFMAs per CU-step.
//  - FC split waves 5/6 (2 K-chunks each, f16 partials summed in phase 2).
// acc/accf lifetimes identical to R5 (reg0-only reset; dead-ish at barrier).
__global__ __launch_bounds__(512, 1) void lstm_fused(
    const float* __restrict__ x, const float* __restrict__ Wih,
    const float* __restrict__ Whh, const float* __restrict__ bih,
    const float* __restrict__ bhh, const float* __restrict__ Wfc,
    const float* __restrict__ bfc, float* __restrict__ out)
{
  // 64 KB: raw x(t) for both rows, f16, slots 13..15 zero
  __shared__ __align__(16) _Float16 xlds[T_][2][16];
  // 64 KB: logits ring, f16: [t][row][part*8 + k], parts summed in phase 2
  __shared__ __align__(16) _Float16 lgring[T_][2][16];
  // 1.3 KB: double-buffered h (cols 0..127 used; stride 168 halfs)
  __shared__ __align__(16) _Float16 abuf[2][2][168];
  // 4.5 KB: xpart ring [buf][row][n16][w*4+ti], stride 36 halfs (=72 B:
  // 18 dwords -> 18*n16 mod 32 hits 16 distinct banks, conflict-free reads)
  __shared__ __align__(16) _Float16 xpring[2][2][16][36];

  const int tid  = threadIdx.x;
  const int wave = tid >> 6;
  const int lane = tid & 63;
  const int n16  = lane & 15;
  const int quad = lane >> 4;
  const int wgb  = blockIdx.x * 2;

  // ---- W fragments: wave w owns gate tiles {w, w+8, w+16, w+24} ----
  // B layout (16x16x32): lane holds B[k = quad*8 + j][n = n16]; h-only K.
  half8 wfrag[4][4];
  #pragma unroll
  for (int ti = 0; ti < 4; ++ti) {
    const int col = (wave + 8 * ti) * 16 + n16;
    #pragma unroll
    for (int kc = 0; kc < 4; ++kc) {
      half8 f;
      #pragma unroll
      for (int j = 0; j < 8; ++j)
        f[j] = (_Float16)Whh[col * H_ + kc * 32 + quad * 8 + j];
      wfrag[ti][kc] = f;
    }
  }
  // xpart weights: thread owns gate col = tid
  float wihv[I_];
  #pragma unroll
  for (int j = 0; j < I_; ++j) wihv[j] = Wih[tid * I_ + j];
  const float biasx = bih[tid] + bhh[tid];
  // xpart ring write offsets (halfs) for rows 0,1
  const int xpw = (tid & 15) * 36 + ((tid >> 4) & 7) * 4 + (tid >> 7);

  // FC: wave 5 owns K-chunks 0,1 (and bias); wave 6 owns K-chunks 2,3.
  const int fcbase = (wave == 6) ? 2 : 0;
  half8 wfc[2];
  const float biasfc = (wave == 5 && n16 < 7) ? bfc[n16] : 0.0f;
  #pragma unroll
  for (int c = 0; c < 2; ++c) {
    half8 f;
    #pragma unroll
    for (int j = 0; j < 8; ++j) {
      const int k = (fcbase + c) * 32 + quad * 8 + j;
      f[j] = (_Float16)((n16 < 7) ? Wfc[n16 * H_ + k] : 0.0f);
    }
    wfc[c] = f;
  }

  // ---- phase 0: preload all x for this WG into LDS (f16), zero pads ----
  for (int idx = tid; idx < T_ * 2 * 16; idx += 512) {
    const int t  = idx >> 5;
    const int rw = (idx >> 4) & 1;
    const int ii = idx & 15;
    float v = 0.0f;
    if (ii < I_) v = x[((size_t)t * B_ + wgb + rw) * I_ + ii];
    xlds[t][rw][ii] = (_Float16)v;
  }
  for (int idx = tid; idx < 2 * 2 * 168; idx += 512)
    ((_Float16*)abuf)[idx] = (_Float16)0.0f;
  __syncthreads();

  // pre-loop: xpart(0) into ring slot 0
  {
    const half8 xa = *(const half8*)&xlds[0][0][0];
    const half8 xb = *(const half8*)&xlds[0][0][8];
    const half8 xc = *(const half8*)&xlds[0][1][0];
    const half8 xd = *(const half8*)&xlds[0][1][8];
    float s0 = biasx, s1 = biasx;
    #pragma unroll
    for (int j = 0; j < 8; ++j) { s0 += (float)xa[j] * wihv[j]; s1 += (float)xc[j] * wihv[j]; }
    #pragma unroll
    for (int j = 0; j < 5; ++j) { s0 += (float)xb[j] * wihv[8 + j]; s1 += (float)xd[j] * wihv[8 + j]; }
    ((_Float16*)xpring[0][0])[xpw] = (_Float16)s0;
    ((_Float16*)xpring[0][1])[xpw] = (_Float16)s1;
  }
  __syncthreads();

  float c_state = 0.0f;           // lanes 0..31: cell (row=quad, j=16w+n16)
  const bool aload = (n16 == 0) || (n16 == 4);
  const int  arow  = n16 >> 2;
  const bool upd   = (lane < 32);
  const bool fcw   = (wave == 5) || (wave == 6);
  const int  rowr  = quad & 1;    // ring-read row (lanes 0-15: 0, 16-31: 1)

  half8 af[4];
  {
    half8 z;
    #pragma unroll
    for (int j = 0; j < 8; ++j) z[j] = (_Float16)0.0f;
    #pragma unroll
    for (int kc = 0; kc < 4; ++kc) af[kc] = z;
  }

  float4_ acc[4];
  #pragma unroll
  for (int ti = 0; ti < 4; ++ti)
    #pragma unroll
    for (int r = 0; r < 4; ++r) acc[ti][r] = 0.0f;
  float4_ accf;
  #pragma unroll
  for (int r = 0; r < 4; ++r) accf[r] = 0.0f;

  // ---- phase 1: the recurrence. No vector-memory ops in this loop. ----
  for (int t = 0; t <= T_; ++t) {
    // h fragments (owner lanes n16==0 -> row 0, n16==4 -> row 1)
    if (aload) {
      #pragma unroll
      for (int kc = 0; kc < 4; ++kc)
        af[kc] = *(const half8*)&abuf[t & 1][arow][kc * 32 + quad * 8];
    }
    // xpart for this step: 4 halfs {ti=0..3}, conflict-free b64
    const half4 xp4 = *(const half4*)&xpring[t & 1][rowr][n16][wave * 4];

    if (t < T_) {
      #pragma unroll
      for (int ti = 0; ti < 4; ++ti) acc[ti][0] = (float)xp4[ti];
      #pragma unroll
      for (int kc = 0; kc < 4; ++kc) {
        #pragma unroll
        for (int ti = 0; ti < 4; ++ti)
          acc[ti] = __builtin_amdgcn_mfma_f32_16x16x32_f16(af[kc],
                        wfrag[ti][kc], acc[ti], 0, 0, 0);
      }
      // cell update from accumulators (lanes 0..31, reg 0;
      // D row = quad*4 + reg -> rows 0,4 = batch rows 0,1)
      if (upd) {
        const float iv = sigmoid_f(acc[0][0]);
        const float fv = sigmoid_f(acc[1][0]);
        const float gv = tanh_f(acc[2][0]);
        const float ov = sigmoid_f(acc[3][0]);
        c_state = fv * c_state + iv * gv;
        abuf[(t + 1) & 1][quad][16 * wave + n16] = (_Float16)(ov * tanh_f(c_state));
      }
      // xpart(t+1) on the VALU (overlaps the MFMA pipe)
      if (t + 1 < T_) {
        const half8 xa = *(const half8*)&xlds[t + 1][0][0];
        const half8 xb = *(const half8*)&xlds[t + 1][0][8];
        const half8 xc = *(const half8*)&xlds[t + 1][1][0];
        const half8 xd = *(const half8*)&xlds[t + 1][1][8];
        float s0 = biasx, s1 = biasx;
        #pragma unroll
        for (int j = 0; j < 8; ++j) { s0 += (float)xa[j] * wihv[j]; s1 += (float)xc[j] * wihv[j]; }
        #pragma unroll
        for (int j = 0; j < 5; ++j) { s0 += (float)xb[j] * wihv[8 + j]; s1 += (float)xd[j] * wihv[8 + j]; }
        ((_Float16*)xpring[(t + 1) & 1][0])[xpw] = (_Float16)s0;
        ((_Float16*)xpring[(t + 1) & 1][1])[xpw] = (_Float16)s1;
      }
    }

    // FC partials: af holds h_t -> logits for output row t-1 (waves 5/6)
    if (fcw && t >= 1) {
      accf[0] = biasfc;
      accf = __builtin_amdgcn_mfma_f32_16x16x32_f16(af[fcbase],
                 wfc[0], accf, 0, 0, 0);
      accf = __builtin_amdgcn_mfma_f32_16x16x32_f16(af[fcbase + 1],
                 wfc[1], accf, 0, 0, 0);
      if (upd && n16 < 7)
        lgring[t - 1][quad][(wave - 5) * 8 + n16] = (_Float16)accf[0];
    }

    __syncthreads();
  }

  // ---- phase 2: softmax of all 2048 logit rows (sum the two halves) ----
  for (int r = tid; r < T_ * 2; r += 512) {
    const int t = r >> 1;
    const int b = r & 1;
    float lg[7];
    float mx = -3.0e38f;
    #pragma unroll
    for (int k = 0; k < 7; ++k) {
      lg[k] = (float)lgring[t][b][k] + (float)lgring[t][b][8 + k];
      mx = fmaxf(mx, lg[k]);
    }
    float s = 0.0f;
    #pragma unroll
    for (int k = 0; k < 7; ++k) {
      lg[k] = fast_exp2(LOG2E * (lg[k] - mx));
      s += lg[k];
    }
    const float rs = fast_rcp(s);
    float* op = &out[((size_t)t * B_ + wgb + b) * 7];
    #pragma unroll
    for (int k = 0; k < 7; ++k) op[k] = lg[k] * rs;
  }
}

extern "C" void kernel_launch(void* const* d_in, const int* in_sizes, int n_in,
                              void* d_out, int out_size, void* d_ws, size_t ws_size,
                              hipStream_t stream) {
  (void)in_sizes; (void)n_in; (void)out_size; (void)d_ws; (void)ws_size;
  const float* x   = (const float*)d_in[0];
  const float* Wih = (const float*)d_in[1];
  const float* Whh = (const float*)d_in[2];
  const float* bih = (const float*)d_in[3];
  const float* bhh = (const float*)d_in[4];
  const float* Wfc = (const float*)d_in[5];
  const float* bfc = (const float*)d_in[6];
  hipLaunchKernelGGL(lstm_fused, dim3(256), dim3(512), 0, stream,
                     x, Wih, Whh, bih, bhh, Wfc, bfc, (float*)d_out);
}